// Round 2
// baseline (51035.648 us; speedup 1.0000x reference)
//
#include <hip/hip_runtime.h>
#include <hip/hip_bf16.h>
#include <hip/hip_cooperative_groups.h>
#include <math.h>

namespace cg = cooperative_groups;

// Problem constants (from reference setup_inputs)
#define BB 4
#define SS 512
#define HH 2048
#define EE 16
#define DD 128
#define GH 2048           // E*D
#define G3 6144           // 3*GH
#define NTOK 2048         // B*S

#define LSTR 132          // LDS leading-dim pad for 128-wide tiles

// ---------------- GEMM 1: C[M,N] = A[M,K] * B[N,K]^T  (both K-major) --------
// xi = x @ w_ih^T.  M=2048, N=6144, K=2048. Tile 128x128, BK=8, 8x8/thread.
__global__ __launch_bounds__(256) void gemm_abt(const float* __restrict__ A,
                                                const float* __restrict__ B,
                                                float* __restrict__ C,
                                                int M, int N, int K) {
  __shared__ float As[8][LSTR];
  __shared__ float Bs[8][LSTR];
  const int bm = blockIdx.y * 128, bn = blockIdx.x * 128;
  const int tid = threadIdx.x;
  const int lm = tid >> 1;          // 0..127 row within tile
  const int kh = (tid & 1) * 4;     // 0 or 4
  const int tx = tid & 15, ty = tid >> 4;
  float acc[8][8] = {};
  const float* Arow = A + (size_t)(bm + lm) * K + kh;
  const float* Brow = B + (size_t)(bn + lm) * K + kh;
  for (int k0 = 0; k0 < K; k0 += 8) {
    float4 av = *(const float4*)(Arow + k0);
    float4 bv = *(const float4*)(Brow + k0);
    As[kh + 0][lm] = av.x; As[kh + 1][lm] = av.y; As[kh + 2][lm] = av.z; As[kh + 3][lm] = av.w;
    Bs[kh + 0][lm] = bv.x; Bs[kh + 1][lm] = bv.y; Bs[kh + 2][lm] = bv.z; Bs[kh + 3][lm] = bv.w;
    __syncthreads();
#pragma unroll
    for (int kk = 0; kk < 8; ++kk) {
      float a8[8], b8[8];
      *(float4*)(a8)     = *(const float4*)(&As[kk][ty * 8]);
      *(float4*)(a8 + 4) = *(const float4*)(&As[kk][ty * 8 + 4]);
      *(float4*)(b8)     = *(const float4*)(&Bs[kk][tx * 8]);
      *(float4*)(b8 + 4) = *(const float4*)(&Bs[kk][tx * 8 + 4]);
#pragma unroll
      for (int i = 0; i < 8; ++i)
#pragma unroll
        for (int j = 0; j < 8; ++j) acc[i][j] = fmaf(a8[i], b8[j], acc[i][j]);
    }
    __syncthreads();
  }
#pragma unroll
  for (int i = 0; i < 8; ++i) {
    float4 v0 = {acc[i][0], acc[i][1], acc[i][2], acc[i][3]};
    float4 v1 = {acc[i][4], acc[i][5], acc[i][6], acc[i][7]};
    float* crow = C + (size_t)(bm + ty * 8 + i) * N + bn + tx * 8;
    *(float4*)(crow)     = v0;
    *(float4*)(crow + 4) = v1;
  }
}

// ---------------- GEMM 2: C[M,N] = A[M,K] * B[K,N] ---------------------------
// expression_logits = x @ w_expr. M=2048, N=2048, K=2048.
__global__ __launch_bounds__(256) void gemm_ab(const float* __restrict__ A,
                                               const float* __restrict__ B,
                                               float* __restrict__ C,
                                               int M, int N, int K) {
  __shared__ float As[8][LSTR];
  __shared__ float Bs[8][LSTR];
  const int bm = blockIdx.y * 128, bn = blockIdx.x * 128;
  const int tid = threadIdx.x;
  const int lm = tid >> 1;
  const int kh = (tid & 1) * 4;
  const int bk = tid >> 5;          // 0..7
  const int bn4 = (tid & 31) * 4;   // 0..124
  const int tx = tid & 15, ty = tid >> 4;
  float acc[8][8] = {};
  const float* Arow = A + (size_t)(bm + lm) * K + kh;
  for (int k0 = 0; k0 < K; k0 += 8) {
    float4 av = *(const float4*)(Arow + k0);
    float4 bv = *(const float4*)(B + (size_t)(k0 + bk) * N + bn + bn4);
    As[kh + 0][lm] = av.x; As[kh + 1][lm] = av.y; As[kh + 2][lm] = av.z; As[kh + 3][lm] = av.w;
    *(float4*)(&Bs[bk][bn4]) = bv;
    __syncthreads();
#pragma unroll
    for (int kk = 0; kk < 8; ++kk) {
      float a8[8], b8[8];
      *(float4*)(a8)     = *(const float4*)(&As[kk][ty * 8]);
      *(float4*)(a8 + 4) = *(const float4*)(&As[kk][ty * 8 + 4]);
      *(float4*)(b8)     = *(const float4*)(&Bs[kk][tx * 8]);
      *(float4*)(b8 + 4) = *(const float4*)(&Bs[kk][tx * 8 + 4]);
#pragma unroll
      for (int i = 0; i < 8; ++i)
#pragma unroll
        for (int j = 0; j < 8; ++j) acc[i][j] = fmaf(a8[i], b8[j], acc[i][j]);
    }
    __syncthreads();
  }
#pragma unroll
  for (int i = 0; i < 8; ++i) {
    float4 v0 = {acc[i][0], acc[i][1], acc[i][2], acc[i][3]};
    float4 v1 = {acc[i][4], acc[i][5], acc[i][6], acc[i][7]};
    float* crow = C + (size_t)(bm + ty * 8 + i) * N + bn + tx * 8;
    *(float4*)(crow)     = v0;
    *(float4*)(crow + 4) = v1;
  }
}

// ---------------- A^T*A loss: sum over (i,j) of (A^T A - I)^2 ---------------
// A = w_expr [K=2048 rows][N=2048 cols]. Never materializes the gram.
__global__ __launch_bounds__(256) void ata_loss(const float* __restrict__ A,
                                                float* __restrict__ el_accum,
                                                int N, int K) {
  __shared__ float As[8][LSTR];
  __shared__ float Bs[8][LSTR];
  __shared__ float red[256];
  const int bi = blockIdx.y * 128, bj = blockIdx.x * 128;
  const int tid = threadIdx.x;
  const int bk = tid >> 5;
  const int bn4 = (tid & 31) * 4;
  const int tx = tid & 15, ty = tid >> 4;
  float acc[8][8] = {};
  for (int k0 = 0; k0 < K; k0 += 8) {
    float4 av = *(const float4*)(A + (size_t)(k0 + bk) * N + bi + bn4);
    float4 bv = *(const float4*)(A + (size_t)(k0 + bk) * N + bj + bn4);
    *(float4*)(&As[bk][bn4]) = av;
    *(float4*)(&Bs[bk][bn4]) = bv;
    __syncthreads();
#pragma unroll
    for (int kk = 0; kk < 8; ++kk) {
      float a8[8], b8[8];
      *(float4*)(a8)     = *(const float4*)(&As[kk][ty * 8]);
      *(float4*)(a8 + 4) = *(const float4*)(&As[kk][ty * 8 + 4]);
      *(float4*)(b8)     = *(const float4*)(&Bs[kk][tx * 8]);
      *(float4*)(b8 + 4) = *(const float4*)(&Bs[kk][tx * 8 + 4]);
#pragma unroll
      for (int i = 0; i < 8; ++i)
#pragma unroll
        for (int j = 0; j < 8; ++j) acc[i][j] = fmaf(a8[i], b8[j], acc[i][j]);
    }
    __syncthreads();
  }
  float local = 0.f;
#pragma unroll
  for (int i = 0; i < 8; ++i) {
#pragma unroll
    for (int j = 0; j < 8; ++j) {
      int gi = bi + ty * 8 + i, gj = bj + tx * 8 + j;
      float d = acc[i][j] - ((gi == gj) ? 1.0f : 0.0f);
      local += d * d;
    }
  }
  red[tid] = local;
  __syncthreads();
  for (int s = 128; s > 0; s >>= 1) {
    if (tid < s) red[tid] += red[tid + s];
    __syncthreads();
  }
  if (tid == 0) atomicAdd(el_accum, red[0]);
}

// ---------------- persistent GRU -------------------------------------------
__device__ inline float wred64(float v) {
#pragma unroll
  for (int o = 32; o; o >>= 1) v += __shfl_xor(v, o);
  return v;
}

// 256 blocks x 512 threads (1 block/CU, all co-resident). Wave w of block bk
// owns output column j = bk*8+w; its 3 w_hh rows (r,z,n) live in registers
// for the whole sequence (k assigned lane-strided: k = c*64+lane).
// h is staged per step into LDS batch-interleaved: hsm[k*4+b], so each
// ds_read_b128 is the standard conflict-free float4 pattern and yields all
// 4 batches for one k (12 FMAs / 16 B read).
__global__ __launch_bounds__(512, 2) void gru_persistent(
    const float* __restrict__ xi,    // [B,S,3GH]
    const float* __restrict__ w_hh,  // [3GH,GH]
    const float* __restrict__ hn,    // [B,GH]
    float* __restrict__ hs) {        // [B,S,GH]
  cg::grid_group grid = cg::this_grid();
  __shared__ __align__(16) float hsm[BB * GH];  // [k][b] interleaved, 32 KB
  const int tid = threadIdx.x;
  const int wave = tid >> 6, lane = tid & 63;
  const int j = blockIdx.x * 8 + wave;

  // weights -> registers (lane-strided k): reg c <-> k = c*64+lane
  float wgr[32], wgz[32], wgn[32];
  {
    const float* pr = w_hh + (size_t)j * GH;
    const float* pz = w_hh + (size_t)(GH + j) * GH;
    const float* pn = w_hh + (size_t)(2 * GH + j) * GH;
#pragma unroll
    for (int c = 0; c < 32; ++c) {
      int k = c * 64 + lane;
      wgr[c] = pr[k]; wgz[c] = pz[k]; wgn[c] = pn[k];
    }
  }
  // initial h from hn, batch-interleaved
#pragma unroll
  for (int i = 0; i < 4; ++i) {
    int k = tid + i * 512;
    float4 v;
    v.x = hn[0 * GH + k]; v.y = hn[1 * GH + k];
    v.z = hn[2 * GH + k]; v.w = hn[3 * GH + k];
    *(float4*)(&hsm[k * 4]) = v;
  }
  __syncthreads();

  for (int s = 0; s < SS; ++s) {
    float ar[BB] = {}, az[BB] = {}, an[BB] = {};
#pragma unroll
    for (int c = 0; c < 32; ++c) {
      float4 h4 = *(const float4*)(&hsm[(c * 64 + lane) * 4]);
      float w_r = wgr[c], w_z = wgz[c], w_n = wgn[c];
      ar[0] = fmaf(w_r, h4.x, ar[0]); az[0] = fmaf(w_z, h4.x, az[0]); an[0] = fmaf(w_n, h4.x, an[0]);
      ar[1] = fmaf(w_r, h4.y, ar[1]); az[1] = fmaf(w_z, h4.y, az[1]); an[1] = fmaf(w_n, h4.y, an[1]);
      ar[2] = fmaf(w_r, h4.z, ar[2]); az[2] = fmaf(w_z, h4.z, az[2]); an[2] = fmaf(w_n, h4.z, an[2]);
      ar[3] = fmaf(w_r, h4.w, ar[3]); az[3] = fmaf(w_z, h4.w, az[3]); an[3] = fmaf(w_n, h4.w, an[3]);
    }
#pragma unroll
    for (int b = 0; b < BB; ++b) { ar[b] = wred64(ar[b]); az[b] = wred64(az[b]); an[b] = wred64(an[b]); }
    if (lane < BB) {
      const int b = lane;
      const float* xrow = xi + ((size_t)(b * SS + s)) * G3;
      float r = 1.0f / (1.0f + expf(-(xrow[j] + ar[b])));
      float z = 1.0f / (1.0f + expf(-(xrow[GH + j] + az[b])));
      float n = tanhf(xrow[2 * GH + j] + r * an[b]);
      float hp = hsm[j * 4 + b];
      hs[((size_t)(b * SS + s)) * GH + j] = (1.0f - z) * n + z * hp;
    }
    if (s + 1 < SS) {
      __threadfence();
      grid.sync();
      __threadfence();
      // restage h(s) from global, batch-interleaved
#pragma unroll
      for (int i = 0; i < 4; ++i) {
        int k = tid + i * 512;
        float4 v;
        v.x = hs[((size_t)(0 * SS + s)) * GH + k];
        v.y = hs[((size_t)(1 * SS + s)) * GH + k];
        v.z = hs[((size_t)(2 * SS + s)) * GH + k];
        v.w = hs[((size_t)(3 * SS + s)) * GH + k];
        *(float4*)(&hsm[k * 4]) = v;
      }
      __syncthreads();
    }
  }
}

// ---------------- per-token: normalize, gram/speciality, cosine --------------
__device__ inline float red16(float v) {
#pragma unroll
  for (int o = 8; o; o >>= 1) v += __shfl_xor(v, o);
  return v;
}

__global__ __launch_bounds__(256) void token_kernel(const float* __restrict__ hs,
                                                    const float* __restrict__ expr,
                                                    float* __restrict__ cos_out,
                                                    float* __restrict__ sp_accum) {
  __shared__ float routn[EE * 132];
  __shared__ float rowc[EE];
  const int t = blockIdx.x;
  const int tid = threadIdx.x;
  const int e = tid >> 4, sub = tid & 15;

  const float* rrow = hs + (size_t)t * GH + e * DD + sub * 8;
  float rv[8];
#pragma unroll
  for (int i = 0; i < 8; ++i) rv[i] = rrow[i];
  float ss = 0.f;
#pragma unroll
  for (int i = 0; i < 8; ++i) ss += rv[i] * rv[i];
  ss = red16(ss);
  float inv = 1.0f / fmaxf(sqrtf(ss), 1e-12f);
#pragma unroll
  for (int i = 0; i < 8; ++i) {
    rv[i] *= inv;
    routn[e * 132 + sub * 8 + i] = rv[i];
  }

  const float* erow = expr + (size_t)t * GH + e * DD + sub * 8;
  float en2 = 0.f, dot = 0.f;
#pragma unroll
  for (int i = 0; i < 8; ++i) {
    float ev = erow[i];
    en2 += ev * ev;
    dot += ev * rv[i];
  }
  en2 = red16(en2);
  dot = red16(dot);
  if (sub == 0) {
    float cosv = dot / fmaxf(sqrtf(en2), 1e-8f);
    cos_out[t * EE + e] = 1.0f - cosv;
  }
  __syncthreads();

  const int f = sub;
  float g = 0.f;
#pragma unroll
  for (int d = 0; d < DD; ++d)
    g = fmaf(routn[e * 132 + d], routn[f * 132 + d], g);
  float diff = g - ((e == f) ? 1.0f : 0.0f);
  float rowsum = red16(diff * diff);
  if (f == 0) {
    float nrm = fmaxf(sqrtf(rowsum), 1e-12f);
    rowc[e] = rowsum / (nrm * nrm);
  }
  __syncthreads();
  if (tid == 0) {
    float tok = 0.f;
#pragma unroll
    for (int i = 0; i < EE; ++i) tok += rowc[i];
    atomicAdd(sp_accum, tok);
  }
}

// ---------------- final: top-2 + softmax + EMA adjust + hn copy + scalars ----
__global__ __launch_bounds__(256) void final_kernel(const float* __restrict__ hs,
                                                    const float* __restrict__ cos_out,
                                                    const float* __restrict__ ema,
                                                    const float* __restrict__ accum,
                                                    float* __restrict__ out_mult,
                                                    float* __restrict__ out_sel,
                                                    float* __restrict__ out_hn,
                                                    float* __restrict__ out_sp,
                                                    float* __restrict__ out_el) {
  const int gtid = blockIdx.x * 256 + threadIdx.x;
  if (gtid < BB * GH) {
    int b = gtid / GH, jj = gtid % GH;
    out_hn[gtid] = hs[((size_t)(b * SS + SS - 1)) * GH + jj];
  }
  if (gtid < NTOK) {
    float sp = accum[0] / (float)NTOK;
    float scale = 1.0f + sp;
    float dv[EE];
#pragma unroll
    for (int e = 0; e < EE; ++e) dv[e] = cos_out[gtid * EE + e] * scale;
    int i0 = 0; float v0 = dv[0];
#pragma unroll
    for (int e = 1; e < EE; ++e) { if (dv[e] > v0) { v0 = dv[e]; i0 = e; } }
    int i1 = -1; float v1 = -1e30f;
#pragma unroll
    for (int e = 0; e < EE; ++e) { if (e != i0 && dv[e] > v1) { v1 = dv[e]; i1 = e; } }
    float ex = expf(v1 - v0);
    float den = 1.0f + ex;
    float m0 = 1.0f / den, m1 = ex / den;
    float total = 0.f;
#pragma unroll
    for (int e = 0; e < EE; ++e) total += ema[e];
    float a0 = 0.f, a1 = 0.f;
    if (total > 0.f) {
      float invt = 1.0f / fmaxf(total, 1e-12f);
      a0 = ema[i0] * invt * 0.01f * (float)EE;
      a1 = ema[i1] * invt * 0.01f * (float)EE;
    }
    out_mult[gtid * 2 + 0] = m0 - a0;
    out_mult[gtid * 2 + 1] = m1 - a1;
    out_sel[gtid * 2 + 0] = (float)i0;
    out_sel[gtid * 2 + 1] = (float)i1;
  }
  if (gtid == 0) {
    out_sp[0] = accum[0] / (float)NTOK;
    out_el[0] = accum[1] / (float)(GH * GH);
  }
}

extern "C" void kernel_launch(void* const* d_in, const int* in_sizes, int n_in,
                              void* d_out, int out_size, void* d_ws, size_t ws_size,
                              hipStream_t stream) {
  const float* x      = (const float*)d_in[0];  // [B,S,H]
  const float* hn     = (const float*)d_in[1];  // [1,B,GH]
  const float* w_ih   = (const float*)d_in[2];  // [3GH,H]
  const float* w_hh   = (const float*)d_in[3];  // [3GH,GH]
  const float* w_expr = (const float*)d_in[4];  // [H,GH]
  const float* ema    = (const float*)d_in[5];  // [E]
  float* out = (float*)d_out;

  float* out_mult = out;                 // 4096
  float* out_sel  = out + 4096;          // 4096
  float* out_expr = out + 8192;          // 4194304
  float* out_hn   = out + 4202496;       // 8192
  float* out_sp   = out + 4210688;       // 1
  float* out_cos  = out + 4210689;       // 32768
  float* out_el   = out + 4243457;       // 1

  float* ws = (float*)d_ws;
  float* xi    = ws;                     // [B,S,3GH] 12,582,912 floats
  float* hs    = ws + 12582912;          // [B,S,GH]   4,194,304 floats
  float* accum = ws + 16777216;          // [0]=sp_sum, [1]=el_sum

  hipMemsetAsync(accum, 0, 2 * sizeof(float), stream);

  // xi = x @ w_ih^T   (M=2048, N=6144, K=2048)
  gemm_abt<<<dim3(G3 / 128, NTOK / 128), 256, 0, stream>>>(x, w_ih, xi, NTOK, G3, HH);

  // expression_logits = x @ w_expr  -> straight to d_out
  gemm_ab<<<dim3(GH / 128, NTOK / 128), 256, 0, stream>>>(x, w_expr, out_expr, NTOK, GH, HH);

  // GRU recurrence: one persistent cooperative kernel, 512 grid syncs
  {
    void* args[] = {(void*)&xi, (void*)&w_hh, (void*)&hn, (void*)&hs};
    hipLaunchCooperativeKernel((void*)gru_persistent, dim3(256), dim3(512),
                               args, 0, stream);
  }

  // expression orthogonality loss
  ata_loss<<<dim3(GH / 128, GH / 128), 256, 0, stream>>>(w_expr, accum + 1, GH, HH);

  // per-token speciality + cosine
  token_kernel<<<NTOK, 256, 0, stream>>>(hs, out_expr, out_cos, accum);

  // final routing + copies + scalars
  final_kernel<<<(BB * GH + 255) / 256, 256, 0, stream>>>(hs, out_cos, ema, accum,
                                                          out_mult, out_sel, out_hn,
                                                          out_sp, out_el);
}

// Round 3
// 7409.389 us; speedup vs baseline: 6.8880x; 6.8880x over previous
//
#include <hip/hip_runtime.h>
#include <hip/hip_bf16.h>
#include <math.h>

// Problem constants (from reference setup_inputs)
#define BB 4
#define SS 512
#define HH 2048
#define EE 16
#define DD 128
#define GH 2048           // E*D
#define G3 6144           // 3*GH
#define NTOK 2048         // B*S

#define LSTR 132          // LDS leading-dim pad for 128-wide tiles

// ---------------- GEMM 1: C[M,N] = A[M,K] * B[N,K]^T  (both K-major) --------
// xi = x @ w_ih^T.  M=2048, N=6144, K=2048. Tile 128x128, BK=8, 8x8/thread.
__global__ __launch_bounds__(256) void gemm_abt(const float* __restrict__ A,
                                                const float* __restrict__ B,
                                                float* __restrict__ C,
                                                int M, int N, int K) {
  __shared__ float As[8][LSTR];
  __shared__ float Bs[8][LSTR];
  const int bm = blockIdx.y * 128, bn = blockIdx.x * 128;
  const int tid = threadIdx.x;
  const int lm = tid >> 1;          // 0..127 row within tile
  const int kh = (tid & 1) * 4;     // 0 or 4
  const int tx = tid & 15, ty = tid >> 4;
  float acc[8][8] = {};
  const float* Arow = A + (size_t)(bm + lm) * K + kh;
  const float* Brow = B + (size_t)(bn + lm) * K + kh;
  for (int k0 = 0; k0 < K; k0 += 8) {
    float4 av = *(const float4*)(Arow + k0);
    float4 bv = *(const float4*)(Brow + k0);
    As[kh + 0][lm] = av.x; As[kh + 1][lm] = av.y; As[kh + 2][lm] = av.z; As[kh + 3][lm] = av.w;
    Bs[kh + 0][lm] = bv.x; Bs[kh + 1][lm] = bv.y; Bs[kh + 2][lm] = bv.z; Bs[kh + 3][lm] = bv.w;
    __syncthreads();
#pragma unroll
    for (int kk = 0; kk < 8; ++kk) {
      float a8[8], b8[8];
      *(float4*)(a8)     = *(const float4*)(&As[kk][ty * 8]);
      *(float4*)(a8 + 4) = *(const float4*)(&As[kk][ty * 8 + 4]);
      *(float4*)(b8)     = *(const float4*)(&Bs[kk][tx * 8]);
      *(float4*)(b8 + 4) = *(const float4*)(&Bs[kk][tx * 8 + 4]);
#pragma unroll
      for (int i = 0; i < 8; ++i)
#pragma unroll
        for (int j = 0; j < 8; ++j) acc[i][j] = fmaf(a8[i], b8[j], acc[i][j]);
    }
    __syncthreads();
  }
#pragma unroll
  for (int i = 0; i < 8; ++i) {
    float4 v0 = {acc[i][0], acc[i][1], acc[i][2], acc[i][3]};
    float4 v1 = {acc[i][4], acc[i][5], acc[i][6], acc[i][7]};
    float* crow = C + (size_t)(bm + ty * 8 + i) * N + bn + tx * 8;
    *(float4*)(crow)     = v0;
    *(float4*)(crow + 4) = v1;
  }
}

// ---------------- GEMM 2: C[M,N] = A[M,K] * B[K,N] ---------------------------
// expression_logits = x @ w_expr. M=2048, N=2048, K=2048.
__global__ __launch_bounds__(256) void gemm_ab(const float* __restrict__ A,
                                               const float* __restrict__ B,
                                               float* __restrict__ C,
                                               int M, int N, int K) {
  __shared__ float As[8][LSTR];
  __shared__ float Bs[8][LSTR];
  const int bm = blockIdx.y * 128, bn = blockIdx.x * 128;
  const int tid = threadIdx.x;
  const int lm = tid >> 1;
  const int kh = (tid & 1) * 4;
  const int bk = tid >> 5;          // 0..7
  const int bn4 = (tid & 31) * 4;   // 0..124
  const int tx = tid & 15, ty = tid >> 4;
  float acc[8][8] = {};
  const float* Arow = A + (size_t)(bm + lm) * K + kh;
  for (int k0 = 0; k0 < K; k0 += 8) {
    float4 av = *(const float4*)(Arow + k0);
    float4 bv = *(const float4*)(B + (size_t)(k0 + bk) * N + bn + bn4);
    As[kh + 0][lm] = av.x; As[kh + 1][lm] = av.y; As[kh + 2][lm] = av.z; As[kh + 3][lm] = av.w;
    *(float4*)(&Bs[bk][bn4]) = bv;
    __syncthreads();
#pragma unroll
    for (int kk = 0; kk < 8; ++kk) {
      float a8[8], b8[8];
      *(float4*)(a8)     = *(const float4*)(&As[kk][ty * 8]);
      *(float4*)(a8 + 4) = *(const float4*)(&As[kk][ty * 8 + 4]);
      *(float4*)(b8)     = *(const float4*)(&Bs[kk][tx * 8]);
      *(float4*)(b8 + 4) = *(const float4*)(&Bs[kk][tx * 8 + 4]);
#pragma unroll
      for (int i = 0; i < 8; ++i)
#pragma unroll
        for (int j = 0; j < 8; ++j) acc[i][j] = fmaf(a8[i], b8[j], acc[i][j]);
    }
    __syncthreads();
  }
#pragma unroll
  for (int i = 0; i < 8; ++i) {
    float4 v0 = {acc[i][0], acc[i][1], acc[i][2], acc[i][3]};
    float4 v1 = {acc[i][4], acc[i][5], acc[i][6], acc[i][7]};
    float* crow = C + (size_t)(bm + ty * 8 + i) * N + bn + tx * 8;
    *(float4*)(crow)     = v0;
    *(float4*)(crow + 4) = v1;
  }
}

// ---------------- A^T*A loss: sum over (i,j) of (A^T A - I)^2 ---------------
__global__ __launch_bounds__(256) void ata_loss(const float* __restrict__ A,
                                                float* __restrict__ el_accum,
                                                int N, int K) {
  __shared__ float As[8][LSTR];
  __shared__ float Bs[8][LSTR];
  __shared__ float red[256];
  const int bi = blockIdx.y * 128, bj = blockIdx.x * 128;
  const int tid = threadIdx.x;
  const int bk = tid >> 5;
  const int bn4 = (tid & 31) * 4;
  const int tx = tid & 15, ty = tid >> 4;
  float acc[8][8] = {};
  for (int k0 = 0; k0 < K; k0 += 8) {
    float4 av = *(const float4*)(A + (size_t)(k0 + bk) * N + bi + bn4);
    float4 bv = *(const float4*)(A + (size_t)(k0 + bk) * N + bj + bn4);
    *(float4*)(&As[bk][bn4]) = av;
    *(float4*)(&Bs[bk][bn4]) = bv;
    __syncthreads();
#pragma unroll
    for (int kk = 0; kk < 8; ++kk) {
      float a8[8], b8[8];
      *(float4*)(a8)     = *(const float4*)(&As[kk][ty * 8]);
      *(float4*)(a8 + 4) = *(const float4*)(&As[kk][ty * 8 + 4]);
      *(float4*)(b8)     = *(const float4*)(&Bs[kk][tx * 8]);
      *(float4*)(b8 + 4) = *(const float4*)(&Bs[kk][tx * 8 + 4]);
#pragma unroll
      for (int i = 0; i < 8; ++i)
#pragma unroll
        for (int j = 0; j < 8; ++j) acc[i][j] = fmaf(a8[i], b8[j], acc[i][j]);
    }
    __syncthreads();
  }
  float local = 0.f;
#pragma unroll
  for (int i = 0; i < 8; ++i) {
#pragma unroll
    for (int j = 0; j < 8; ++j) {
      int gi = bi + ty * 8 + i, gj = bj + tx * 8 + j;
      float d = acc[i][j] - ((gi == gj) ? 1.0f : 0.0f);
      local += d * d;
    }
  }
  red[tid] = local;
  __syncthreads();
  for (int s = 128; s > 0; s >>= 1) {
    if (tid < s) red[tid] += red[tid + s];
    __syncthreads();
  }
  if (tid == 0) atomicAdd(el_accum, red[0]);
}

// ---------------- persistent GRU with fence-free barrier ---------------------
__device__ inline float wred64(float v) {
#pragma unroll
  for (int o = 32; o; o >>= 1) v += __shfl_xor(v, o);
  return v;
}

// 256 blocks x 512 threads, cooperative (co-residency guaranteed).
// Wave w of block bk owns column j = bk*8+w; its 3 w_hh rows live in
// registers (lane-strided k) for the whole sequence.
// Barrier: h published via agent-scope relaxed atomic stores (write-through
// to L3 -> NO buffer_wbl2 fence needed). __syncthreads drains vmcnt before
// the leader bumps a monotone device-scope counter; readers spin relaxed.
// Restage reads are plain coalesced loads (addresses fresh this kernel;
// L2s invalidated at dispatch; data is in L3 via write-through).
__global__ __launch_bounds__(512, 2) void gru_persistent(
    const float* __restrict__ xi,    // [B,S,3GH]
    const float* __restrict__ w_hh,  // [3GH,GH]
    const float* __restrict__ hn,    // [B,GH]
    float* __restrict__ hs,          // [B,S,GH]
    int* __restrict__ bar) {         // monotone barrier counter (zeroed)
  __shared__ __align__(16) float hsm[BB * GH];  // [k][b] interleaved, 32 KB
  const int tid = threadIdx.x;
  const int wave = tid >> 6, lane = tid & 63;
  const int j = blockIdx.x * 8 + wave;
  const int nblk = gridDim.x;

  // weights -> registers (lane-strided k): reg c <-> k = c*64+lane
  float wgr[32], wgz[32], wgn[32];
  {
    const float* pr = w_hh + (size_t)j * GH;
    const float* pz = w_hh + (size_t)(GH + j) * GH;
    const float* pn = w_hh + (size_t)(2 * GH + j) * GH;
#pragma unroll
    for (int c = 0; c < 32; ++c) {
      int k = c * 64 + lane;
      wgr[c] = pr[k]; wgz[c] = pz[k]; wgn[c] = pn[k];
    }
  }
  // initial h from hn, batch-interleaved
#pragma unroll
  for (int i = 0; i < 4; ++i) {
    int k = tid + i * 512;
    float4 v;
    v.x = hn[0 * GH + k]; v.y = hn[1 * GH + k];
    v.z = hn[2 * GH + k]; v.w = hn[3 * GH + k];
    *(float4*)(&hsm[k * 4]) = v;
  }
  __syncthreads();

  for (int s = 0; s < SS; ++s) {
    // prefetch xi gate inputs early (hides global latency behind the dots)
    float xr = 0.f, xz = 0.f, xn_ = 0.f;
    if (lane < BB) {
      const float* xrow = xi + ((size_t)(lane * SS + s)) * G3;
      xr  = xrow[j];
      xz  = xrow[GH + j];
      xn_ = xrow[2 * GH + j];
    }

    float ar[BB] = {}, az[BB] = {}, an[BB] = {};
#pragma unroll
    for (int c = 0; c < 32; ++c) {
      float4 h4 = *(const float4*)(&hsm[(c * 64 + lane) * 4]);
      float w_r = wgr[c], w_z = wgz[c], w_n = wgn[c];
      ar[0] = fmaf(w_r, h4.x, ar[0]); az[0] = fmaf(w_z, h4.x, az[0]); an[0] = fmaf(w_n, h4.x, an[0]);
      ar[1] = fmaf(w_r, h4.y, ar[1]); az[1] = fmaf(w_z, h4.y, az[1]); an[1] = fmaf(w_n, h4.y, an[1]);
      ar[2] = fmaf(w_r, h4.z, ar[2]); az[2] = fmaf(w_z, h4.z, az[2]); an[2] = fmaf(w_n, h4.z, an[2]);
      ar[3] = fmaf(w_r, h4.w, ar[3]); az[3] = fmaf(w_z, h4.w, az[3]); an[3] = fmaf(w_n, h4.w, an[3]);
    }
#pragma unroll
    for (int b = 0; b < BB; ++b) { ar[b] = wred64(ar[b]); az[b] = wred64(az[b]); an[b] = wred64(an[b]); }

    if (lane < BB) {
      const int b = lane;
      float r = 1.0f / (1.0f + expf(-(xr + ar[b])));
      float z = 1.0f / (1.0f + expf(-(xz + az[b])));
      float n = tanhf(xn_ + r * an[b]);
      float hp = hsm[j * 4 + b];
      float hv = (1.0f - z) * n + z * hp;
      // write-through store (agent scope): visible at L3, no fence needed
      __hip_atomic_store(hs + ((size_t)(b * SS + s)) * GH + j, hv,
                         __ATOMIC_RELAXED, __HIP_MEMORY_SCOPE_AGENT);
    }

    if (s + 1 < SS) {
      __syncthreads();  // drains vmcnt for every wave's stores before arrival
      if (tid == 0) {
        __hip_atomic_fetch_add(bar, 1, __ATOMIC_RELAXED, __HIP_MEMORY_SCOPE_AGENT);
        const int target = nblk * (s + 1);
        while (__hip_atomic_load(bar, __ATOMIC_RELAXED, __HIP_MEMORY_SCOPE_AGENT) < target) { }
      }
      __syncthreads();
      // restage h(s) from global, batch-interleaved (coalesced per stream)
#pragma unroll
      for (int i = 0; i < 4; ++i) {
        int k = tid + i * 512;
        float4 v;
        v.x = hs[((size_t)(0 * SS + s)) * GH + k];
        v.y = hs[((size_t)(1 * SS + s)) * GH + k];
        v.z = hs[((size_t)(2 * SS + s)) * GH + k];
        v.w = hs[((size_t)(3 * SS + s)) * GH + k];
        *(float4*)(&hsm[k * 4]) = v;
      }
      __syncthreads();
    }
  }
}

// ---------------- per-token: normalize, gram/speciality, cosine --------------
__device__ inline float red16(float v) {
#pragma unroll
  for (int o = 8; o; o >>= 1) v += __shfl_xor(v, o);
  return v;
}

__global__ __launch_bounds__(256) void token_kernel(const float* __restrict__ hs,
                                                    const float* __restrict__ expr,
                                                    float* __restrict__ cos_out,
                                                    float* __restrict__ sp_accum) {
  __shared__ float routn[EE * 132];
  __shared__ float rowc[EE];
  const int t = blockIdx.x;
  const int tid = threadIdx.x;
  const int e = tid >> 4, sub = tid & 15;

  const float* rrow = hs + (size_t)t * GH + e * DD + sub * 8;
  float rv[8];
#pragma unroll
  for (int i = 0; i < 8; ++i) rv[i] = rrow[i];
  float ss = 0.f;
#pragma unroll
  for (int i = 0; i < 8; ++i) ss += rv[i] * rv[i];
  ss = red16(ss);
  float inv = 1.0f / fmaxf(sqrtf(ss), 1e-12f);
#pragma unroll
  for (int i = 0; i < 8; ++i) {
    rv[i] *= inv;
    routn[e * 132 + sub * 8 + i] = rv[i];
  }

  const float* erow = expr + (size_t)t * GH + e * DD + sub * 8;
  float en2 = 0.f, dot = 0.f;
#pragma unroll
  for (int i = 0; i < 8; ++i) {
    float ev = erow[i];
    en2 += ev * ev;
    dot += ev * rv[i];
  }
  en2 = red16(en2);
  dot = red16(dot);
  if (sub == 0) {
    float cosv = dot / fmaxf(sqrtf(en2), 1e-8f);
    cos_out[t * EE + e] = 1.0f - cosv;
  }
  __syncthreads();

  const int f = sub;
  float g = 0.f;
#pragma unroll
  for (int d = 0; d < DD; ++d)
    g = fmaf(routn[e * 132 + d], routn[f * 132 + d], g);
  float diff = g - ((e == f) ? 1.0f : 0.0f);
  float rowsum = red16(diff * diff);
  if (f == 0) {
    float nrm = fmaxf(sqrtf(rowsum), 1e-12f);
    rowc[e] = rowsum / (nrm * nrm);
  }
  __syncthreads();
  if (tid == 0) {
    float tok = 0.f;
#pragma unroll
    for (int i = 0; i < EE; ++i) tok += rowc[i];
    atomicAdd(sp_accum, tok);
  }
}

// ---------------- final: top-2 + softmax + EMA adjust + hn copy + scalars ----
__global__ __launch_bounds__(256) void final_kernel(const float* __restrict__ hs,
                                                    const float* __restrict__ cos_out,
                                                    const float* __restrict__ ema,
                                                    const float* __restrict__ accum,
                                                    float* __restrict__ out_mult,
                                                    float* __restrict__ out_sel,
                                                    float* __restrict__ out_hn,
                                                    float* __restrict__ out_sp,
                                                    float* __restrict__ out_el) {
  const int gtid = blockIdx.x * 256 + threadIdx.x;
  if (gtid < BB * GH) {
    int b = gtid / GH, jj = gtid % GH;
    out_hn[gtid] = hs[((size_t)(b * SS + SS - 1)) * GH + jj];
  }
  if (gtid < NTOK) {
    float sp = accum[0] / (float)NTOK;
    float scale = 1.0f + sp;
    float dv[EE];
#pragma unroll
    for (int e = 0; e < EE; ++e) dv[e] = cos_out[gtid * EE + e] * scale;
    int i0 = 0; float v0 = dv[0];
#pragma unroll
    for (int e = 1; e < EE; ++e) { if (dv[e] > v0) { v0 = dv[e]; i0 = e; } }
    int i1 = -1; float v1 = -1e30f;
#pragma unroll
    for (int e = 0; e < EE; ++e) { if (e != i0 && dv[e] > v1) { v1 = dv[e]; i1 = e; } }
    float ex = expf(v1 - v0);
    float den = 1.0f + ex;
    float m0 = 1.0f / den, m1 = ex / den;
    float total = 0.f;
#pragma unroll
    for (int e = 0; e < EE; ++e) total += ema[e];
    float a0 = 0.f, a1 = 0.f;
    if (total > 0.f) {
      float invt = 1.0f / fmaxf(total, 1e-12f);
      a0 = ema[i0] * invt * 0.01f * (float)EE;
      a1 = ema[i1] * invt * 0.01f * (float)EE;
    }
    out_mult[gtid * 2 + 0] = m0 - a0;
    out_mult[gtid * 2 + 1] = m1 - a1;
    out_sel[gtid * 2 + 0] = (float)i0;
    out_sel[gtid * 2 + 1] = (float)i1;
  }
  if (gtid == 0) {
    out_sp[0] = accum[0] / (float)NTOK;
    out_el[0] = accum[1] / (float)(GH * GH);
  }
}

extern "C" void kernel_launch(void* const* d_in, const int* in_sizes, int n_in,
                              void* d_out, int out_size, void* d_ws, size_t ws_size,
                              hipStream_t stream) {
  const float* x      = (const float*)d_in[0];  // [B,S,H]
  const float* hn     = (const float*)d_in[1];  // [1,B,GH]
  const float* w_ih   = (const float*)d_in[2];  // [3GH,H]
  const float* w_hh   = (const float*)d_in[3];  // [3GH,GH]
  const float* w_expr = (const float*)d_in[4];  // [H,GH]
  const float* ema    = (const float*)d_in[5];  // [E]
  float* out = (float*)d_out;

  float* out_mult = out;                 // 4096
  float* out_sel  = out + 4096;          // 4096
  float* out_expr = out + 8192;          // 4194304
  float* out_hn   = out + 4202496;       // 8192
  float* out_sp   = out + 4210688;       // 1
  float* out_cos  = out + 4210689;       // 32768
  float* out_el   = out + 4243457;       // 1

  float* ws = (float*)d_ws;
  float* xi    = ws;                     // [B,S,3GH] 12,582,912 floats
  float* hs    = ws + 12582912;          // [B,S,GH]   4,194,304 floats
  float* accum = ws + 16777216;          // [0]=sp_sum, [1]=el_sum
  int*   bar   = (int*)(ws + 16777218);  // barrier counter

  hipMemsetAsync(accum, 0, 3 * sizeof(float), stream);  // accum + bar

  // xi = x @ w_ih^T   (M=2048, N=6144, K=2048)
  gemm_abt<<<dim3(G3 / 128, NTOK / 128), 256, 0, stream>>>(x, w_ih, xi, NTOK, G3, HH);

  // expression_logits = x @ w_expr  -> straight to d_out
  gemm_ab<<<dim3(GH / 128, NTOK / 128), 256, 0, stream>>>(x, w_expr, out_expr, NTOK, GH, HH);

  // GRU recurrence: persistent cooperative kernel, fence-free barrier
  {
    void* args[] = {(void*)&xi, (void*)&w_hh, (void*)&hn, (void*)&hs, (void*)&bar};
    hipLaunchCooperativeKernel((void*)gru_persistent, dim3(256), dim3(512),
                               args, 0, stream);
  }

  // expression orthogonality loss
  ata_loss<<<dim3(GH / 128, GH / 128), 256, 0, stream>>>(w_expr, accum + 1, GH, HH);

  // per-token speciality + cosine
  token_kernel<<<NTOK, 256, 0, stream>>>(hs, out_expr, out_cos, accum);

  // final routing + copies + scalars
  final_kernel<<<(BB * GH + 255) / 256, 256, 0, stream>>>(hs, out_cos, ema, accum,
                                                          out_mult, out_sel, out_hn,
                                                          out_sp, out_el);
}

// Round 4
// 4669.406 us; speedup vs baseline: 10.9298x; 1.5868x over previous
//
#include <hip/hip_runtime.h>
#include <hip/hip_bf16.h>
#include <math.h>

// Problem constants (from reference setup_inputs)
#define BB 4
#define SS 512
#define HH 2048
#define EE 16
#define DD 128
#define GH 2048           // E*D
#define G3 6144           // 3*GH
#define NTOK 2048         // B*S

#define LSTR 132          // LDS leading-dim pad for 128-wide tiles
#define FPAD 32           // flag padding: one flag per 128 B

// ---------------- GEMM 1: C[M,N] = A[M,K] * B[N,K]^T  (both K-major) --------
// xi = x @ w_ih^T.  M=2048, N=6144, K=2048. Tile 128x128, BK=8, 8x8/thread.
__global__ __launch_bounds__(256) void gemm_abt(const float* __restrict__ A,
                                                const float* __restrict__ B,
                                                float* __restrict__ C,
                                                int M, int N, int K) {
  __shared__ float As[8][LSTR];
  __shared__ float Bs[8][LSTR];
  const int bm = blockIdx.y * 128, bn = blockIdx.x * 128;
  const int tid = threadIdx.x;
  const int lm = tid >> 1;          // 0..127 row within tile
  const int kh = (tid & 1) * 4;     // 0 or 4
  const int tx = tid & 15, ty = tid >> 4;
  float acc[8][8] = {};
  const float* Arow = A + (size_t)(bm + lm) * K + kh;
  const float* Brow = B + (size_t)(bn + lm) * K + kh;
  for (int k0 = 0; k0 < K; k0 += 8) {
    float4 av = *(const float4*)(Arow + k0);
    float4 bv = *(const float4*)(Brow + k0);
    As[kh + 0][lm] = av.x; As[kh + 1][lm] = av.y; As[kh + 2][lm] = av.z; As[kh + 3][lm] = av.w;
    Bs[kh + 0][lm] = bv.x; Bs[kh + 1][lm] = bv.y; Bs[kh + 2][lm] = bv.z; Bs[kh + 3][lm] = bv.w;
    __syncthreads();
#pragma unroll
    for (int kk = 0; kk < 8; ++kk) {
      float a8[8], b8[8];
      *(float4*)(a8)     = *(const float4*)(&As[kk][ty * 8]);
      *(float4*)(a8 + 4) = *(const float4*)(&As[kk][ty * 8 + 4]);
      *(float4*)(b8)     = *(const float4*)(&Bs[kk][tx * 8]);
      *(float4*)(b8 + 4) = *(const float4*)(&Bs[kk][tx * 8 + 4]);
#pragma unroll
      for (int i = 0; i < 8; ++i)
#pragma unroll
        for (int j = 0; j < 8; ++j) acc[i][j] = fmaf(a8[i], b8[j], acc[i][j]);
    }
    __syncthreads();
  }
#pragma unroll
  for (int i = 0; i < 8; ++i) {
    float4 v0 = {acc[i][0], acc[i][1], acc[i][2], acc[i][3]};
    float4 v1 = {acc[i][4], acc[i][5], acc[i][6], acc[i][7]};
    float* crow = C + (size_t)(bm + ty * 8 + i) * N + bn + tx * 8;
    *(float4*)(crow)     = v0;
    *(float4*)(crow + 4) = v1;
  }
}

// ---------------- GEMM 2: C[M,N] = A[M,K] * B[K,N] ---------------------------
// expression_logits = x @ w_expr. M=2048, N=2048, K=2048.
__global__ __launch_bounds__(256) void gemm_ab(const float* __restrict__ A,
                                               const float* __restrict__ B,
                                               float* __restrict__ C,
                                               int M, int N, int K) {
  __shared__ float As[8][LSTR];
  __shared__ float Bs[8][LSTR];
  const int bm = blockIdx.y * 128, bn = blockIdx.x * 128;
  const int tid = threadIdx.x;
  const int lm = tid >> 1;
  const int kh = (tid & 1) * 4;
  const int bk = tid >> 5;          // 0..7
  const int bn4 = (tid & 31) * 4;   // 0..124
  const int tx = tid & 15, ty = tid >> 4;
  float acc[8][8] = {};
  const float* Arow = A + (size_t)(bm + lm) * K + kh;
  for (int k0 = 0; k0 < K; k0 += 8) {
    float4 av = *(const float4*)(Arow + k0);
    float4 bv = *(const float4*)(B + (size_t)(k0 + bk) * N + bn + bn4);
    As[kh + 0][lm] = av.x; As[kh + 1][lm] = av.y; As[kh + 2][lm] = av.z; As[kh + 3][lm] = av.w;
    *(float4*)(&Bs[bk][bn4]) = bv;
    __syncthreads();
#pragma unroll
    for (int kk = 0; kk < 8; ++kk) {
      float a8[8], b8[8];
      *(float4*)(a8)     = *(const float4*)(&As[kk][ty * 8]);
      *(float4*)(a8 + 4) = *(const float4*)(&As[kk][ty * 8 + 4]);
      *(float4*)(b8)     = *(const float4*)(&Bs[kk][tx * 8]);
      *(float4*)(b8 + 4) = *(const float4*)(&Bs[kk][tx * 8 + 4]);
#pragma unroll
      for (int i = 0; i < 8; ++i)
#pragma unroll
        for (int j = 0; j < 8; ++j) acc[i][j] = fmaf(a8[i], b8[j], acc[i][j]);
    }
    __syncthreads();
  }
#pragma unroll
  for (int i = 0; i < 8; ++i) {
    float4 v0 = {acc[i][0], acc[i][1], acc[i][2], acc[i][3]};
    float4 v1 = {acc[i][4], acc[i][5], acc[i][6], acc[i][7]};
    float* crow = C + (size_t)(bm + ty * 8 + i) * N + bn + tx * 8;
    *(float4*)(crow)     = v0;
    *(float4*)(crow + 4) = v1;
  }
}

// ---------------- A^T*A loss: sum over (i,j) of (A^T A - I)^2 ---------------
__global__ __launch_bounds__(256) void ata_loss(const float* __restrict__ A,
                                                float* __restrict__ el_accum,
                                                int N, int K) {
  __shared__ float As[8][LSTR];
  __shared__ float Bs[8][LSTR];
  __shared__ float red[256];
  const int bi = blockIdx.y * 128, bj = blockIdx.x * 128;
  const int tid = threadIdx.x;
  const int bk = tid >> 5;
  const int bn4 = (tid & 31) * 4;
  const int tx = tid & 15, ty = tid >> 4;
  float acc[8][8] = {};
  for (int k0 = 0; k0 < K; k0 += 8) {
    float4 av = *(const float4*)(A + (size_t)(k0 + bk) * N + bi + bn4);
    float4 bv = *(const float4*)(A + (size_t)(k0 + bk) * N + bj + bn4);
    *(float4*)(&As[bk][bn4]) = av;
    *(float4*)(&Bs[bk][bn4]) = bv;
    __syncthreads();
#pragma unroll
    for (int kk = 0; kk < 8; ++kk) {
      float a8[8], b8[8];
      *(float4*)(a8)     = *(const float4*)(&As[kk][ty * 8]);
      *(float4*)(a8 + 4) = *(const float4*)(&As[kk][ty * 8 + 4]);
      *(float4*)(b8)     = *(const float4*)(&Bs[kk][tx * 8]);
      *(float4*)(b8 + 4) = *(const float4*)(&Bs[kk][tx * 8 + 4]);
#pragma unroll
      for (int i = 0; i < 8; ++i)
#pragma unroll
        for (int j = 0; j < 8; ++j) acc[i][j] = fmaf(a8[i], b8[j], acc[i][j]);
    }
    __syncthreads();
  }
  float local = 0.f;
#pragma unroll
  for (int i = 0; i < 8; ++i) {
#pragma unroll
    for (int j = 0; j < 8; ++j) {
      int gi = bi + ty * 8 + i, gj = bj + tx * 8 + j;
      float d = acc[i][j] - ((gi == gj) ? 1.0f : 0.0f);
      local += d * d;
    }
  }
  red[tid] = local;
  __syncthreads();
  for (int s = 128; s > 0; s >>= 1) {
    if (tid < s) red[tid] += red[tid + s];
    __syncthreads();
  }
  if (tid == 0) atomicAdd(el_accum, red[0]);
}

// ---------------- persistent GRU with RMW-free flag barrier ------------------
__device__ inline float wred64(float v) {
#pragma unroll
  for (int o = 32; o; o >>= 1) v += __shfl_xor(v, o);
  return v;
}

// 256 blocks x 512 threads, cooperative (co-residency guaranteed).
// Wave w of block bk owns column j = bk*8+w; its 3 w_hh rows live in
// registers (lane-strided k) for the whole sequence.
// Barrier (no RMW): each block STORES monotone epoch s+1 to its own
// 128B-padded flag (256 parallel lines, no L3 same-line serialization).
// Wait: wave 0's 64 lanes sweep all 256 flags per poll round (4 overlapped
// agent loads/lane), wave-min, release via __syncthreads.
// Visibility: h published via write-through agent stores; __syncthreads
// drains vmcnt before the flag store; hs addresses for step s are touched
// exactly once ever, so plain restage loads can't hit stale L1/L2 lines.
__global__ __launch_bounds__(512, 2) void gru_persistent(
    const float* __restrict__ xi,    // [B,S,3GH]
    const float* __restrict__ w_hh,  // [3GH,GH]
    const float* __restrict__ hn,    // [B,GH]
    float* __restrict__ hs,          // [B,S,GH]
    int* __restrict__ flags) {       // [256*FPAD], zeroed
  __shared__ __align__(16) float hsm[BB * GH];  // [k][b] interleaved, 32 KB
  const int tid = threadIdx.x;
  const int wave = tid >> 6, lane = tid & 63;
  const int j = blockIdx.x * 8 + wave;

  // weights -> registers (lane-strided k): reg c <-> k = c*64+lane
  float wgr[32], wgz[32], wgn[32];
  {
    const float* pr = w_hh + (size_t)j * GH;
    const float* pz = w_hh + (size_t)(GH + j) * GH;
    const float* pn = w_hh + (size_t)(2 * GH + j) * GH;
#pragma unroll
    for (int c = 0; c < 32; ++c) {
      int k = c * 64 + lane;
      wgr[c] = pr[k]; wgz[c] = pz[k]; wgn[c] = pn[k];
    }
  }
  // initial h from hn, batch-interleaved
#pragma unroll
  for (int i = 0; i < 4; ++i) {
    int k = tid + i * 512;
    float4 v;
    v.x = hn[0 * GH + k]; v.y = hn[1 * GH + k];
    v.z = hn[2 * GH + k]; v.w = hn[3 * GH + k];
    *(float4*)(&hsm[k * 4]) = v;
  }
  __syncthreads();

  for (int s = 0; s < SS; ++s) {
    // prefetch xi gate inputs early (latency hidden behind the dot loop)
    float xr = 0.f, xz = 0.f, xn_ = 0.f;
    if (lane < BB) {
      const float* xrow = xi + ((size_t)(lane * SS + s)) * G3;
      xr  = xrow[j];
      xz  = xrow[GH + j];
      xn_ = xrow[2 * GH + j];
    }

    float ar[BB] = {}, az[BB] = {}, an[BB] = {};
#pragma unroll
    for (int c = 0; c < 32; ++c) {
      float4 h4 = *(const float4*)(&hsm[(c * 64 + lane) * 4]);
      float w_r = wgr[c], w_z = wgz[c], w_n = wgn[c];
      ar[0] = fmaf(w_r, h4.x, ar[0]); az[0] = fmaf(w_z, h4.x, az[0]); an[0] = fmaf(w_n, h4.x, an[0]);
      ar[1] = fmaf(w_r, h4.y, ar[1]); az[1] = fmaf(w_z, h4.y, az[1]); an[1] = fmaf(w_n, h4.y, an[1]);
      ar[2] = fmaf(w_r, h4.z, ar[2]); az[2] = fmaf(w_z, h4.z, az[2]); an[2] = fmaf(w_n, h4.z, an[2]);
      ar[3] = fmaf(w_r, h4.w, ar[3]); az[3] = fmaf(w_z, h4.w, az[3]); an[3] = fmaf(w_n, h4.w, an[3]);
    }
#pragma unroll
    for (int b = 0; b < BB; ++b) { ar[b] = wred64(ar[b]); az[b] = wred64(az[b]); an[b] = wred64(an[b]); }

    if (lane < BB) {
      const int b = lane;
      float r = 1.0f / (1.0f + expf(-(xr + ar[b])));
      float z = 1.0f / (1.0f + expf(-(xz + az[b])));
      float n = tanhf(xn_ + r * an[b]);
      float hp = hsm[j * 4 + b];
      float hv = (1.0f - z) * n + z * hp;
      // write-through store (agent scope): visible at L3, no fence needed
      __hip_atomic_store(hs + ((size_t)(b * SS + s)) * GH + j, hv,
                         __ATOMIC_RELAXED, __HIP_MEMORY_SCOPE_AGENT);
    }

    if (s + 1 < SS) {
      __syncthreads();  // drains vmcnt: every wave's h stores are at L3
      if (tid == 0)
        __hip_atomic_store(&flags[blockIdx.x * FPAD], s + 1,
                           __ATOMIC_RELAXED, __HIP_MEMORY_SCOPE_AGENT);
      if (wave == 0) {
        const int target = s + 1;
        for (;;) {
          int m0 = __hip_atomic_load(&flags[(lane      ) * FPAD], __ATOMIC_RELAXED, __HIP_MEMORY_SCOPE_AGENT);
          int m1 = __hip_atomic_load(&flags[(lane +  64) * FPAD], __ATOMIC_RELAXED, __HIP_MEMORY_SCOPE_AGENT);
          int m2 = __hip_atomic_load(&flags[(lane + 128) * FPAD], __ATOMIC_RELAXED, __HIP_MEMORY_SCOPE_AGENT);
          int m3 = __hip_atomic_load(&flags[(lane + 192) * FPAD], __ATOMIC_RELAXED, __HIP_MEMORY_SCOPE_AGENT);
          int mn = min(min(m0, m1), min(m2, m3));
#pragma unroll
          for (int o = 32; o; o >>= 1) mn = min(mn, __shfl_xor(mn, o));
          if (mn >= target) break;
        }
      }
      __syncthreads();  // release whole block; all h(s) visible
      // restage h(s) from global, batch-interleaved (coalesced per stream)
#pragma unroll
      for (int i = 0; i < 4; ++i) {
        int k = tid + i * 512;
        float4 v;
        v.x = hs[((size_t)(0 * SS + s)) * GH + k];
        v.y = hs[((size_t)(1 * SS + s)) * GH + k];
        v.z = hs[((size_t)(2 * SS + s)) * GH + k];
        v.w = hs[((size_t)(3 * SS + s)) * GH + k];
        *(float4*)(&hsm[k * 4]) = v;
      }
      __syncthreads();
    }
  }
}

// ---------------- per-token: normalize, gram/speciality, cosine --------------
__device__ inline float red16(float v) {
#pragma unroll
  for (int o = 8; o; o >>= 1) v += __shfl_xor(v, o);
  return v;
}

__global__ __launch_bounds__(256) void token_kernel(const float* __restrict__ hs,
                                                    const float* __restrict__ expr,
                                                    float* __restrict__ cos_out,
                                                    float* __restrict__ sp_accum) {
  __shared__ float routn[EE * 132];
  __shared__ float rowc[EE];
  const int t = blockIdx.x;
  const int tid = threadIdx.x;
  const int e = tid >> 4, sub = tid & 15;

  const float* rrow = hs + (size_t)t * GH + e * DD + sub * 8;
  float rv[8];
#pragma unroll
  for (int i = 0; i < 8; ++i) rv[i] = rrow[i];
  float ss = 0.f;
#pragma unroll
  for (int i = 0; i < 8; ++i) ss += rv[i] * rv[i];
  ss = red16(ss);
  float inv = 1.0f / fmaxf(sqrtf(ss), 1e-12f);
#pragma unroll
  for (int i = 0; i < 8; ++i) {
    rv[i] *= inv;
    routn[e * 132 + sub * 8 + i] = rv[i];
  }

  const float* erow = expr + (size_t)t * GH + e * DD + sub * 8;
  float en2 = 0.f, dot = 0.f;
#pragma unroll
  for (int i = 0; i < 8; ++i) {
    float ev = erow[i];
    en2 += ev * ev;
    dot += ev * rv[i];
  }
  en2 = red16(en2);
  dot = red16(dot);
  if (sub == 0) {
    float cosv = dot / fmaxf(sqrtf(en2), 1e-8f);
    cos_out[t * EE + e] = 1.0f - cosv;
  }
  __syncthreads();

  const int f = sub;
  float g = 0.f;
#pragma unroll
  for (int d = 0; d < DD; ++d)
    g = fmaf(routn[e * 132 + d], routn[f * 132 + d], g);
  float diff = g - ((e == f) ? 1.0f : 0.0f);
  float rowsum = red16(diff * diff);
  if (f == 0) {
    float nrm = fmaxf(sqrtf(rowsum), 1e-12f);
    rowc[e] = rowsum / (nrm * nrm);
  }
  __syncthreads();
  if (tid == 0) {
    float tok = 0.f;
#pragma unroll
    for (int i = 0; i < EE; ++i) tok += rowc[i];
    atomicAdd(sp_accum, tok);
  }
}

// ---------------- final: top-2 + softmax + EMA adjust + hn copy + scalars ----
__global__ __launch_bounds__(256) void final_kernel(const float* __restrict__ hs,
                                                    const float* __restrict__ cos_out,
                                                    const float* __restrict__ ema,
                                                    const float* __restrict__ accum,
                                                    float* __restrict__ out_mult,
                                                    float* __restrict__ out_sel,
                                                    float* __restrict__ out_hn,
                                                    float* __restrict__ out_sp,
                                                    float* __restrict__ out_el) {
  const int gtid = blockIdx.x * 256 + threadIdx.x;
  if (gtid < BB * GH) {
    int b = gtid / GH, jj = gtid % GH;
    out_hn[gtid] = hs[((size_t)(b * SS + SS - 1)) * GH + jj];
  }
  if (gtid < NTOK) {
    float sp = accum[0] / (float)NTOK;
    float scale = 1.0f + sp;
    float dv[EE];
#pragma unroll
    for (int e = 0; e < EE; ++e) dv[e] = cos_out[gtid * EE + e] * scale;
    int i0 = 0; float v0 = dv[0];
#pragma unroll
    for (int e = 1; e < EE; ++e) { if (dv[e] > v0) { v0 = dv[e]; i0 = e; } }
    int i1 = -1; float v1 = -1e30f;
#pragma unroll
    for (int e = 0; e < EE; ++e) { if (e != i0 && dv[e] > v1) { v1 = dv[e]; i1 = e; } }
    float ex = expf(v1 - v0);
    float den = 1.0f + ex;
    float m0 = 1.0f / den, m1 = ex / den;
    float total = 0.f;
#pragma unroll
    for (int e = 0; e < EE; ++e) total += ema[e];
    float a0 = 0.f, a1 = 0.f;
    if (total > 0.f) {
      float invt = 1.0f / fmaxf(total, 1e-12f);
      a0 = ema[i0] * invt * 0.01f * (float)EE;
      a1 = ema[i1] * invt * 0.01f * (float)EE;
    }
    out_mult[gtid * 2 + 0] = m0 - a0;
    out_mult[gtid * 2 + 1] = m1 - a1;
    out_sel[gtid * 2 + 0] = (float)i0;
    out_sel[gtid * 2 + 1] = (float)i1;
  }
  if (gtid == 0) {
    out_sp[0] = accum[0] / (float)NTOK;
    out_el[0] = accum[1] / (float)(GH * GH);
  }
}

extern "C" void kernel_launch(void* const* d_in, const int* in_sizes, int n_in,
                              void* d_out, int out_size, void* d_ws, size_t ws_size,
                              hipStream_t stream) {
  const float* x      = (const float*)d_in[0];  // [B,S,H]
  const float* hn     = (const float*)d_in[1];  // [1,B,GH]
  const float* w_ih   = (const float*)d_in[2];  // [3GH,H]
  const float* w_hh   = (const float*)d_in[3];  // [3GH,GH]
  const float* w_expr = (const float*)d_in[4];  // [H,GH]
  const float* ema    = (const float*)d_in[5];  // [E]
  float* out = (float*)d_out;

  float* out_mult = out;                 // 4096
  float* out_sel  = out + 4096;          // 4096
  float* out_expr = out + 8192;          // 4194304
  float* out_hn   = out + 4202496;       // 8192
  float* out_sp   = out + 4210688;       // 1
  float* out_cos  = out + 4210689;       // 32768
  float* out_el   = out + 4243457;       // 1

  float* ws = (float*)d_ws;
  float* xi    = ws;                     // [B,S,3GH] 12,582,912 floats
  float* hs    = ws + 12582912;          // [B,S,GH]   4,194,304 floats
  float* accum = ws + 16777216;          // [0]=sp_sum, [1]=el_sum
  int*   flags = (int*)(ws + 16777220);  // 256*FPAD ints, 128B-padded flags

  // zero accum (2 floats) + pad + flags (256*FPAD ints)
  hipMemsetAsync(accum, 0, (4 + 256 * FPAD) * sizeof(float), stream);

  // xi = x @ w_ih^T   (M=2048, N=6144, K=2048)
  gemm_abt<<<dim3(G3 / 128, NTOK / 128), 256, 0, stream>>>(x, w_ih, xi, NTOK, G3, HH);

  // expression_logits = x @ w_expr  -> straight to d_out
  gemm_ab<<<dim3(GH / 128, NTOK / 128), 256, 0, stream>>>(x, w_expr, out_expr, NTOK, GH, HH);

  // GRU recurrence: persistent cooperative kernel, RMW-free flag barrier
  {
    void* args[] = {(void*)&xi, (void*)&w_hh, (void*)&hn, (void*)&hs, (void*)&flags};
    hipLaunchCooperativeKernel((void*)gru_persistent, dim3(256), dim3(512),
                               args, 0, stream);
  }

  // expression orthogonality loss
  ata_loss<<<dim3(GH / 128, GH / 128), 256, 0, stream>>>(w_expr, accum + 1, GH, HH);

  // per-token speciality + cosine
  token_kernel<<<NTOK, 256, 0, stream>>>(hs, out_expr, out_cos, accum);

  // final routing + copies + scalars
  final_kernel<<<(BB * GH + 255) / 256, 256, 0, stream>>>(hs, out_cos, ema, accum,
                                                          out_mult, out_sel, out_hn,
                                                          out_sp, out_el);
}